// Round 3
// baseline (747.711 us; speedup 1.0000x reference)
//
#include <hip/hip_runtime.h>

#define BB 8
#define MM 4096
#define EE 2048
#define DD 128

typedef _Float16 f16x8 __attribute__((ext_vector_type(8)));
typedef _Float16 f16x4 __attribute__((ext_vector_type(4)));
typedef float    f32x4 __attribute__((ext_vector_type(4)));

// ---------------------------------------------------------------------------
// bitpack: inc [8][4096][2048] fp32 (binary) -> bits, one uint64 per 64 e.
// Wave reads 64 consecutive floats (256 B, coalesced), ballot packs, lane 0
// writes. Pure HBM stream: the only 268-MB pass in the pipeline.
// ---------------------------------------------------------------------------
__global__ __launch_bounds__(256) void bitpack(const float* __restrict__ inc,
                                               unsigned long long* __restrict__ bits)
{
    const int wid  = (blockIdx.x * 256 + threadIdx.x) >> 6;
    const int lane = threadIdx.x & 63;
    const int nw   = (gridDim.x * 256) >> 6;
    const int total = BB * MM * (EE / 64);   // 1M words
    for (int w = wid; w < total; w += nw){
        float v = inc[(size_t)w * 64 + lane];
        unsigned long long m = __ballot(v != 0.0f);
        if (lane == 0) bits[w] = m;
    }
}

// ---------------------------------------------------------------------------
// transpose_to16: src [R][C] fp32 -> dst [C][R] f16, batch = blockIdx.y.
// ---------------------------------------------------------------------------
__global__ __launch_bounds__(256) void transpose_to16(const float* __restrict__ src,
                                                      _Float16* __restrict__ dst,
                                                      int R, int C)
{
    __shared__ alignas(16) float tile[64 * 67];
    const int tilesC = C >> 6;
    const int r0 = (blockIdx.x / tilesC) << 6;
    const int c0 = (blockIdx.x % tilesC) << 6;
    const float* s = src + (size_t)blockIdx.y * R * C;
    _Float16*   d = dst + (size_t)blockIdx.y * R * C;
    const int t = threadIdx.x;
    #pragma unroll
    for (int i = 0; i < 4; i++){
        int idx = t + 256 * i;
        int r = idx >> 4, c4 = idx & 15;
        float4 v = *(const float4*)(s + (size_t)(r0 + r) * C + c0 + c4 * 4);
        tile[(c4 * 4 + 0) * 67 + r] = v.x;
        tile[(c4 * 4 + 1) * 67 + r] = v.y;
        tile[(c4 * 4 + 2) * 67 + r] = v.z;
        tile[(c4 * 4 + 3) * 67 + r] = v.w;
    }
    __syncthreads();
    #pragma unroll
    for (int i = 0; i < 2; i++){
        int idx = t + 256 * i;
        int row = idx >> 3, rb = idx & 7;
        f16x8 h;
        #pragma unroll
        for (int j = 0; j < 8; j++) h[j] = (_Float16)tile[row * 67 + rb * 8 + j];
        *(f16x8*)(d + (size_t)(c0 + row) * R + r0 + rb * 8) = h;
    }
}

// ---------------------------------------------------------------------------
// big1: agg[b][e][d] = sum_m inc(m,e) * feat[m][d]
// A = featT f16 [d][m] (XOR-swizzled b128), B = bits -> f16 0/1 in LDS [m][e].
// Tile 128 d x 32 e, BK = 64 m. grid (64, 8) = 512 blocks = 2/CU.
// Epilogue: LDS transpose -> agg[e][d] with full-line float4 stores.
// ---------------------------------------------------------------------------
__global__ __launch_bounds__(256) void big1(const _Float16* __restrict__ featT,
                                            const unsigned* __restrict__ bits32,
                                            float* __restrict__ agg)
{
    __shared__ alignas(16) char smem[21 * 1024];
    _Float16* lA = (_Float16*)smem;                // [128][64] XOR, 16 KB
    _Float16* lB = (_Float16*)(smem + 16384);      // [64][32] pitch 36, 4.5 KB
    float*    sT = (float*)smem;                   // epilogue [32][132], 16.9 KB

    const int b  = blockIdx.y;
    const int e0 = blockIdx.x * 32;
    const int ew32 = blockIdx.x;                   // uint32 word index along e
    const _Float16* fT = featT  + (size_t)b * DD * MM;
    const unsigned* bp = bits32 + (size_t)b * MM * (EE / 32);
    float*          op = agg    + (size_t)b * EE * DD;

    const int t = threadIdx.x;
    const int lane = t & 63;
    const int fr = lane & 15, q = lane >> 4;
    const int wd = ((t >> 6) >> 1) * 64;
    const int we = ((t >> 6) & 1) * 16;

    f32x4 acc[4] = {};
    uint4 ra[4];
    unsigned bw;

    const int sm_ = t >> 2;            // staging m row 0..63
    const int se8 = (t & 3) * 8;       // staging e offset {0,8,16,24}

    auto loadg = [&](int k0){
        #pragma unroll
        for (int i = 0; i < 4; i++){
            int idx = t + 256 * i;
            int dd = idx >> 3, kb = idx & 7;
            ra[i] = *(const uint4*)(fT + (size_t)dd * MM + k0 + kb * 8);
        }
        bw = bp[(size_t)(k0 + sm_) * (EE / 32) + ew32];
    };
    auto stores = [&](){
        #pragma unroll
        for (int i = 0; i < 4; i++){
            int idx = t + 256 * i;
            int dd = idx >> 3, kb = idx & 7;
            *(uint4*)&lA[dd * 64 + ((kb ^ (dd & 7)) * 8)] = ra[i];
        }
        unsigned byte = (bw >> se8) & 0xFFu;
        f16x4 h0, h1;
        #pragma unroll
        for (int j = 0; j < 4; j++){
            h0[j] = (_Float16)(float)((byte >> j) & 1u);
            h1[j] = (_Float16)(float)((byte >> (j + 4)) & 1u);
        }
        *(f16x4*)&lB[sm_ * 36 + se8]     = h0;
        *(f16x4*)&lB[sm_ * 36 + se8 + 4] = h1;
    };

    const int nchunk = MM / 64;
    loadg(0);
    for (int c = 0; c < nchunk; c++){
        __syncthreads();
        stores();
        __syncthreads();
        if (c + 1 < nchunk) loadg((c + 1) * 64);
        #pragma unroll
        for (int h = 0; h < 2; h++){
            f16x8 bfr;
            #pragma unroll
            for (int j = 0; j < 8; j++)
                bfr[j] = lB[(h * 32 + q * 8 + j) * 36 + we + fr];
            const int kb = h * 4 + q;
            #pragma unroll
            for (int r = 0; r < 4; r++){
                int row = wd + r * 16 + fr;
                f16x8 afr = *(const f16x8*)&lA[row * 64 + ((kb ^ (row & 7)) * 8)];
                acc[r] = __builtin_amdgcn_mfma_f32_16x16x32_f16(afr, bfr, acc[r], 0, 0, 0);
            }
        }
    }
    // Epilogue: D[row=d][col=e] -> LDS -> agg[e][d] full-line float4 stores.
    __syncthreads();
    #pragma unroll
    for (int r = 0; r < 4; r++){
        int el = we + fr;
        #pragma unroll
        for (int reg = 0; reg < 4; reg++)
            sT[el * 132 + wd + r * 16 + q * 4 + reg] = acc[r][reg];
    }
    __syncthreads();
    #pragma unroll
    for (int i = 0; i < 4; i++){
        int idx = t + 256 * i;
        int el = idx >> 5, d4 = idx & 31;
        float4 v = *(const float4*)&sT[el * 132 + d4 * 4];
        *(float4*)(op + (size_t)(e0 + el) * DD + d4 * 4) = v;
    }
}

// ---------------------------------------------------------------------------
// big2: node[b][m][d] = sum_e inc(m,e) * ef2[e][d]
// A = bits -> f16 0/1 in LDS [m][e] (XOR), B = ef2T f16 [d][e] (XOR).
// Tile 64 m x 128 d, BK = 64 e. grid (64, 8) = 512 blocks.
// Epilogue: LDS staged, full-line float4 stores (2 halves of 32 m).
// ---------------------------------------------------------------------------
__global__ __launch_bounds__(256) void big2(const unsigned* __restrict__ bits32,
                                            const _Float16* __restrict__ ef2T,
                                            float* __restrict__ node)
{
    __shared__ alignas(16) char smem[24 * 1024];
    _Float16* lA = (_Float16*)smem;                // [64][64] XOR, 8 KB
    _Float16* lB = (_Float16*)(smem + 8192);       // [128][64] XOR, 16 KB
    float*    sT = (float*)smem;                   // epilogue [32][132], 16.9 KB

    const int b  = blockIdx.y;
    const int m0 = blockIdx.x * 64;
    const unsigned* bp = bits32 + (size_t)b * MM * (EE / 32);
    const _Float16* eT = ef2T   + (size_t)b * DD * EE;
    float*          op = node   + (size_t)b * MM * DD;

    const int t = threadIdx.x;
    const int lane = t & 63;
    const int fr = lane & 15, q = lane >> 4;
    const int wc = (t >> 6) * 32;

    f32x4 acc[4][2] = {};
    uint4 rbv[4];
    unsigned bw;

    const int sm_  = t >> 2;        // staging m row 0..63
    const int ssub = t & 3;         // 16 e-bits each

    auto loadg = [&](int k0){
        #pragma unroll
        for (int i = 0; i < 4; i++){
            int idx = t + 256 * i;
            int dd = idx >> 3, kb = idx & 7;
            rbv[i] = *(const uint4*)(eT + (size_t)dd * EE + k0 + kb * 8);
        }
        bw = bp[(size_t)(m0 + sm_) * (EE / 32) + (k0 >> 5) + (ssub >> 1)];
    };
    auto stores = [&](){
        #pragma unroll
        for (int i = 0; i < 4; i++){
            int idx = t + 256 * i;
            int dd = idx >> 3, kb = idx & 7;
            *(uint4*)&lB[dd * 64 + ((kb ^ (dd & 7)) * 8)] = rbv[i];
        }
        unsigned v16 = (bw >> ((ssub & 1) * 16)) & 0xFFFFu;
        #pragma unroll
        for (int half = 0; half < 2; half++){
            f16x8 h;
            #pragma unroll
            for (int j = 0; j < 8; j++)
                h[j] = (_Float16)(float)((v16 >> (half * 8 + j)) & 1u);
            int kb = ssub * 2 + half;
            *(f16x8*)&lA[sm_ * 64 + ((kb ^ (sm_ & 7)) * 8)] = h;
        }
    };

    const int nchunk = EE / 64;
    loadg(0);
    for (int c = 0; c < nchunk; c++){
        __syncthreads();
        stores();
        __syncthreads();
        if (c + 1 < nchunk) loadg((c + 1) * 64);
        #pragma unroll
        for (int h = 0; h < 2; h++){
            const int kb = h * 4 + q;
            f16x8 bfr[2];
            #pragma unroll
            for (int cc = 0; cc < 2; cc++){
                int col = wc + cc * 16 + fr;
                bfr[cc] = *(const f16x8*)&lB[col * 64 + ((kb ^ (col & 7)) * 8)];
            }
            #pragma unroll
            for (int r = 0; r < 4; r++){
                int row = r * 16 + fr;
                f16x8 afr = *(const f16x8*)&lA[row * 64 + ((kb ^ (row & 7)) * 8)];
                #pragma unroll
                for (int cc = 0; cc < 2; cc++)
                    acc[r][cc] = __builtin_amdgcn_mfma_f32_16x16x32_f16(afr, bfr[cc], acc[r][cc], 0, 0, 0);
            }
        }
    }
    // Epilogue in two 32-m halves through LDS -> full-line float4 stores.
    #pragma unroll
    for (int rh = 0; rh < 2; rh++){
        __syncthreads();
        #pragma unroll
        for (int rr = 0; rr < 2; rr++){
            int r = rh * 2 + rr;
            #pragma unroll
            for (int cc = 0; cc < 2; cc++){
                int col = wc + cc * 16 + fr;
                #pragma unroll
                for (int reg = 0; reg < 4; reg++)
                    sT[(rr * 16 + q * 4 + reg) * 132 + col] = acc[r][cc][reg];
            }
        }
        __syncthreads();
        #pragma unroll
        for (int i = 0; i < 4; i++){
            int idx = t + 256 * i;
            int ml = idx >> 5, d4 = idx & 31;
            float4 v = *(const float4*)&sT[ml * 132 + d4 * 4];
            *(float4*)(op + (size_t)(m0 + rh * 32 + ml) * DD + d4 * 4) = v;
        }
    }
}

// ---------------------------------------------------------------------------
// rowmm (verified): C[n,:] = A[n,:] @ W^T, fp32.
// ---------------------------------------------------------------------------
__global__ __launch_bounds__(256) void rowmm(const float* __restrict__ A,
                                             const float* __restrict__ W,
                                             float* __restrict__ C)
{
    __shared__ alignas(16) float lA[32][132];
    __shared__ alignas(16) float lW[64][140];
    const int t = threadIdx.x;
    const int row0 = blockIdx.x * 32;
    const float4* A4 = (const float4*)A;
    const float4* W4 = (const float4*)W;

    #pragma unroll
    for (int i = 0; i < 4; i++){
        int idx = t + 256 * i;
        int r = idx >> 5, k4 = idx & 31;
        *(float4*)&lA[r][k4 * 4] = A4[(size_t)(row0 + r) * 32 + k4];
    }
    const int qq = t >> 5;
    const int cc = t & 31;

    #pragma unroll
    for (int ph = 0; ph < 2; ph++){
        __syncthreads();
        #pragma unroll
        for (int i = 0; i < 8; i++){
            int idx = t + 256 * i;
            int c = idx >> 5, k4 = idx & 31;
            *(float4*)&lW[c][k4 * 4] = W4[(size_t)(ph * 64 + c) * 32 + k4];
        }
        __syncthreads();
        float s[4][2] = {};
        for (int k4 = 0; k4 < 32; k4++){
            float4 w0 = *(const float4*)&lW[cc][k4 * 4];
            float4 w1 = *(const float4*)&lW[cc + 32][k4 * 4];
            #pragma unroll
            for (int j = 0; j < 4; j++){
                float4 a = *(const float4*)&lA[qq + 8 * j][k4 * 4];
                s[j][0] += a.x * w0.x + a.y * w0.y + a.z * w0.z + a.w * w0.w;
                s[j][1] += a.x * w1.x + a.y * w1.y + a.z * w1.z + a.w * w1.w;
            }
        }
        #pragma unroll
        for (int j = 0; j < 4; j++){
            size_t ro = (size_t)(row0 + qq + 8 * j) * DD + ph * 64;
            C[ro + cc]      = s[j][0];
            C[ro + cc + 32] = s[j][1];
        }
    }
}

// ---------------------------------------------------------------------------
// Online softmax over e (two passes, coalesced).
// ---------------------------------------------------------------------------
__global__ __launch_bounds__(256) void sm_part(const float* __restrict__ eatt,
                                               float* __restrict__ part)
{
    const int b = blockIdx.x, slab = blockIdx.y;
    const int t = threadIdx.x;
    const int dl = t & 127, eh = t >> 7;
    const size_t base = (size_t)b * EE * DD + dl;
    const int e0 = slab * 256;
    float m = -1e30f;
    for (int s = 0; s < 128; s++)
        m = fmaxf(m, eatt[base + (size_t)(e0 + eh + 2 * s) * DD]);
    float l = 0.f;
    for (int s = 0; s < 128; s++)
        l += __expf(eatt[base + (size_t)(e0 + eh + 2 * s) * DD] - m);
    __shared__ float red[2][128][2];
    red[eh][dl][0] = m; red[eh][dl][1] = l;
    __syncthreads();
    if (t < 128){
        float m0 = red[0][t][0], l0 = red[0][t][1];
        float m1 = red[1][t][0], l1 = red[1][t][1];
        float M = fmaxf(m0, m1);
        float L = l0 * __expf(m0 - M) + l1 * __expf(m1 - M);
        float* p = part + ((size_t)(b * 8 + slab) * DD + t) * 2;
        p[0] = M; p[1] = L;
    }
}

__global__ __launch_bounds__(256) void sm_apply(float* __restrict__ eatt,
                                                const float* __restrict__ agg,
                                                const float* __restrict__ part)
{
    const int b = blockIdx.x, sl = blockIdx.y;
    const int t = threadIdx.x;
    __shared__ float mv[128], iv[128];
    if (t < 128){
        float mbuf[8], lbuf[8];
        float M = -1e30f;
        #pragma unroll
        for (int s = 0; s < 8; s++){
            const float* p = part + ((size_t)(b * 8 + s) * DD + t) * 2;
            mbuf[s] = p[0]; lbuf[s] = p[1];
            M = fmaxf(M, mbuf[s]);
        }
        float L = 0.f;
        #pragma unroll
        for (int s = 0; s < 8; s++) L += lbuf[s] * __expf(mbuf[s] - M);
        mv[t] = M; iv[t] = 1.f / L;
    }
    __syncthreads();
    const int dl = t & 127, eh = t >> 7;
    const size_t base = (size_t)b * EE * DD + dl;
    const int e0 = sl * 128;
    for (int s = 0; s < 64; s++){
        size_t ix = base + (size_t)(e0 + eh + 2 * s) * DD;
        eatt[ix] = agg[ix] * __expf(eatt[ix] - mv[dl]) * iv[dl];
    }
}

// ---------------------------------------------------------------------------
// Pipeline (layer recursion is a fixed point; ec_Wa is dead code):
//  0. bits = bitpack(inc)                      [the only 268-MB pass]
//  1. featT = T(feat) f16                      2. agg = feat^T-sum via bits
//  3. eatt = agg @ vWa^T                       4. softmax -> P (in-place)
//  5. edge = P @ vWp^T (output 2)              6. ef2 = edge @ eWp^T
//  7. ef2T = T(ef2) f16                        8. node = bits @ ef2 (output 1)
// Scratch: ws[0,8M)=bits (live to end), ws[8,16M)=agg then ef2T;
// node_out[0,8M)=featT then ef2; node_out[8,16M)=eatt/P; part in edge region.
// ---------------------------------------------------------------------------
extern "C" void kernel_launch(void* const* d_in, const int* in_sizes, int n_in,
                              void* d_out, int out_size, void* d_ws, size_t ws_size,
                              hipStream_t stream)
{
    const float* feat = (const float*)d_in[0];
    const float* inc  = (const float*)d_in[1];
    const float* vWa  = (const float*)d_in[2];
    const float* vWp  = (const float*)d_in[3];
    const float* eWp  = (const float*)d_in[6];

    float* node_out = (float*)d_out;                        // [8,4096,128]
    float* edge_out = node_out + (size_t)BB * MM * DD;      // [8,2048,128]

    char* w = (char*)d_ws;
    unsigned long long* bits = (unsigned long long*)w;      // 8 MB, live to end
    float*    agg  = (float*)(w + ((size_t)8 << 20));       // 8 MB
    _Float16* ef2T = (_Float16*)(w + ((size_t)8 << 20));    // 4 MB (over dead agg)

    _Float16* featT = (_Float16*)node_out;                  // node[0,8M) scratch
    float*    ef2   = node_out;                             // node[0,8M), after featT dead
    float*    eattP = node_out + (size_t)BB * EE * DD;      // node[8,16M) scratch
    float*    part  = edge_out;                             // 64 KB, dead before step 5

    dim3 blk(256);

    // 0. bitpack
    bitpack<<<dim3(2048), blk, 0, stream>>>(inc, bits);
    // 1. featT = f16(feat^T)
    transpose_to16<<<dim3((MM / 64) * (DD / 64), BB), blk, 0, stream>>>(feat, featT, MM, DD);
    // 2. agg[e][d] = sum_m inc(m,e) feat[m][d]
    big1<<<dim3(EE / 32, BB), blk, 0, stream>>>(featT, (const unsigned*)bits, agg);
    // 3. eatt = agg @ vWa^T
    rowmm<<<dim3(BB * EE / 32), blk, 0, stream>>>(agg, vWa, eattP);
    // 4. P = agg * softmax_e(eatt)
    sm_part <<<dim3(BB, 8),  blk, 0, stream>>>(eattP, part);
    sm_apply<<<dim3(BB, 16), blk, 0, stream>>>(eattP, agg, part);
    // 5. edge_feats = P @ vWp^T  -> output 2
    rowmm<<<dim3(BB * EE / 32), blk, 0, stream>>>(eattP, vWp, edge_out);
    // 6. ef2 = edge_feats @ eWp^T
    rowmm<<<dim3(BB * EE / 32), blk, 0, stream>>>(edge_out, eWp, ef2);
    // 7. ef2T = f16(ef2^T)
    transpose_to16<<<dim3((EE / 64) * (DD / 64), BB), blk, 0, stream>>>(ef2, ef2T, EE, DD);
    // 8. node_feats = inc @ ef2  -> output 1
    big2<<<dim3(MM / 64, BB), blk, 0, stream>>>((const unsigned*)bits, ef2T, node_out);
}

// Round 4
// 634.808 us; speedup vs baseline: 1.1779x; 1.1779x over previous
//
#include <hip/hip_runtime.h>

#define BB 8
#define MM 4096
#define EE 2048
#define DD 128

typedef _Float16 f16x8 __attribute__((ext_vector_type(8)));
typedef float    f32x4 __attribute__((ext_vector_type(4)));

// ---------------------------------------------------------------------------
// bitpack: inc [8][4096][2048] fp32 (binary) -> bits[m][e-words], uint64 per
// 64 e. The only 268-MB pass in the pipeline.
// ---------------------------------------------------------------------------
__global__ __launch_bounds__(256) void bitpack(const float* __restrict__ inc,
                                               unsigned long long* __restrict__ bits)
{
    const int wid  = (blockIdx.x * 256 + threadIdx.x) >> 6;
    const int lane = threadIdx.x & 63;
    const int nw   = (gridDim.x * 256) >> 6;
    const int total = BB * MM * (EE / 64);
    for (int w = wid; w < total; w += nw){
        float v = inc[(size_t)w * 64 + lane];
        unsigned long long m = __ballot(v != 0.0f);
        if (lane == 0) bits[w] = m;
    }
}

// ---------------------------------------------------------------------------
// bit_transpose: bits[m][e-bits] -> bitsT[e][m-bits] via per-wave 64x64
// bit-tile ballot transpose. Lane=m on load, lane=e on store; both coalesced.
// ---------------------------------------------------------------------------
__global__ __launch_bounds__(256) void bit_transpose(const unsigned long long* __restrict__ bits,
                                                     unsigned long long* __restrict__ bitsT)
{
    const int b = blockIdx.z;
    const int w = threadIdx.x >> 6;
    const int lane = threadIdx.x & 63;
    const int m0 = (blockIdx.y * 4 + w) * 64;
    const int e0 = blockIdx.x * 64;
    unsigned long long v = bits[((size_t)b * MM + m0 + lane) * (EE / 64) + (e0 >> 6)];
    unsigned long long mine = 0;
    #pragma unroll
    for (int e = 0; e < 64; e++){
        unsigned long long bal = __ballot((v >> e) & 1ull);
        if (lane == e) mine = bal;
    }
    bitsT[((size_t)b * EE + e0 + lane) * (MM / 64) + (m0 >> 6)] = mine;
}

// ---------------------------------------------------------------------------
// transpose_to16: src [R][C] fp32 -> dst [C][R] f16, batch = blockIdx.y.
// ---------------------------------------------------------------------------
__global__ __launch_bounds__(256) void transpose_to16(const float* __restrict__ src,
                                                      _Float16* __restrict__ dst,
                                                      int R, int C)
{
    __shared__ alignas(16) float tile[64 * 67];
    const int tilesC = C >> 6;
    const int r0 = (blockIdx.x / tilesC) << 6;
    const int c0 = (blockIdx.x % tilesC) << 6;
    const float* s = src + (size_t)blockIdx.y * R * C;
    _Float16*   d = dst + (size_t)blockIdx.y * R * C;
    const int t = threadIdx.x;
    #pragma unroll
    for (int i = 0; i < 4; i++){
        int idx = t + 256 * i;
        int r = idx >> 4, c4 = idx & 15;
        float4 v = *(const float4*)(s + (size_t)(r0 + r) * C + c0 + c4 * 4);
        tile[(c4 * 4 + 0) * 67 + r] = v.x;
        tile[(c4 * 4 + 1) * 67 + r] = v.y;
        tile[(c4 * 4 + 2) * 67 + r] = v.z;
        tile[(c4 * 4 + 3) * 67 + r] = v.w;
    }
    __syncthreads();
    #pragma unroll
    for (int i = 0; i < 2; i++){
        int idx = t + 256 * i;
        int row = idx >> 3, rb = idx & 7;
        f16x8 h;
        #pragma unroll
        for (int j = 0; j < 8; j++) h[j] = (_Float16)tile[row * 67 + rb * 8 + j];
        *(f16x8*)(d + (size_t)(c0 + row) * R + r0 + rb * 8) = h;
    }
}

// ---------------------------------------------------------------------------
// bitgemm: out[b,z][row][d] = sum_{k in slice} bit(row,k) * dense[d][k]
//   bitsrc: uint4 rows [R][Ktot/128]  (bit k of row)
//   dense : f16 [128 d][Ktot]
// Tile 128 rows x 128 d, BK=128, double-buffered LDS, 1 barrier/chunk.
// A-frags expanded from raw bits in registers (no LDS transpose).
// grid (R/128, BB, nslice); block 256 (4 waves, wave-tile 32 rows x 128 d).
// ---------------------------------------------------------------------------
__global__ __launch_bounds__(256) void bitgemm(const uint4* __restrict__ bitsrc,
                                               const _Float16* __restrict__ dense,
                                               float* __restrict__ out,
                                               int R, int Ktot, int Kslice,
                                               unsigned sliceStride)
{
    __shared__ alignas(16) char smem[69632];
    _Float16* lD0 = (_Float16*)smem;                 // [128][128] f16, XOR-swizzled
    _Float16* lD1 = (_Float16*)(smem + 32768);
    uint4* lB0 = (uint4*)(smem + 65536);             // [128] rows x 128 bits
    uint4* lB1 = (uint4*)(smem + 65536 + 2048);

    const int b = blockIdx.y;
    const int row0 = blockIdx.x * 128;
    const int PB = Ktot >> 7;                        // uint4 per bit-row
    const uint4* bp = bitsrc + (size_t)b * R * PB + (size_t)row0 * PB;
    const _Float16* dp = dense + (size_t)b * 128 * Ktot;
    float* op = out + (size_t)blockIdx.z * sliceStride
                    + (size_t)b * R * 128 + (size_t)row0 * 128;

    const int kbase = blockIdx.z * Kslice;
    const int nchunk = Kslice >> 7;

    const int t = threadIdx.x;
    const int lane = t & 63;
    const int w = t >> 6;
    const int fr = lane & 15, q = lane >> 4;
    const int q8 = q * 8;

    f32x4 acc[2][8] = {};
    uint4 rd[8];
    uint4 rb;

    auto loadg = [&](int kg){
        #pragma unroll
        for (int i = 0; i < 8; i++){
            int idx = t + 256 * i;
            int dd = idx >> 4, kb = idx & 15;
            rd[i] = *(const uint4*)(dp + (size_t)dd * Ktot + kg + kb * 8);
        }
        if (t < 128) rb = bp[(size_t)t * PB + (kg >> 7)];
    };
    auto stage = [&](int buf){
        _Float16* lD = buf ? lD1 : lD0;
        uint4* lB = buf ? lB1 : lB0;
        #pragma unroll
        for (int i = 0; i < 8; i++){
            int idx = t + 256 * i;
            int dd = idx >> 4, kb = idx & 15;
            *(uint4*)&lD[dd * 128 + ((kb ^ (dd & 7)) * 8)] = rd[i];
        }
        if (t < 128) lB[t] = rb;
    };
    auto compute = [&](int buf){
        const _Float16* lD = buf ? lD1 : lD0;
        const uint4* lB = buf ? lB1 : lB0;
        uint4 bw[2];
        #pragma unroll
        for (int r = 0; r < 2; r++)
            bw[r] = lB[w * 32 + r * 16 + fr];        // b128, q-broadcast
        #pragma unroll
        for (int h = 0; h < 4; h++){
            f16x8 af[2];
            #pragma unroll
            for (int r = 0; r < 2; r++){
                unsigned word = ((const unsigned*)&bw[r])[h];
                unsigned byte = (word >> q8) & 0xFFu;
                #pragma unroll
                for (int j = 0; j < 8; j++)
                    af[r][j] = (_Float16)(float)((byte >> j) & 1u);
            }
            #pragma unroll
            for (int c = 0; c < 8; c++){
                int row = c * 16 + fr;
                f16x8 bf = *(const f16x8*)&lD[row * 128 + (((h * 4 + q) ^ (row & 7)) * 8)];
                #pragma unroll
                for (int r = 0; r < 2; r++)
                    acc[r][c] = __builtin_amdgcn_mfma_f32_16x16x32_f16(af[r], bf, acc[r][c], 0, 0, 0);
            }
        }
    };

    loadg(kbase);
    stage(0);
    __syncthreads();
    for (int c = 0; c < nchunk; c++){
        if (c + 1 < nchunk) loadg(kbase + (c + 1) * 128);   // prefetch under compute
        compute(c & 1);
        if (c + 1 < nchunk) stage((c + 1) & 1);             // other buffer: safe pre-barrier
        __syncthreads();
    }
    // Epilogue: stage [128][132] fp32 in LDS, then full-line float4 stores.
    float* sT = (float*)smem;
    #pragma unroll
    for (int r = 0; r < 2; r++)
        #pragma unroll
        for (int c = 0; c < 8; c++)
            #pragma unroll
            for (int reg = 0; reg < 4; reg++)
                sT[(w * 32 + r * 16 + q * 4 + reg) * 132 + c * 16 + fr] = acc[r][c][reg];
    __syncthreads();
    #pragma unroll
    for (int i = 0; i < 16; i++){
        int idx = t + 256 * i;
        int row = idx >> 5, c4 = idx & 31;
        float4 v = *(const float4*)&sT[row * 132 + c4 * 4];
        *(float4*)(op + (size_t)row * 128 + c4 * 4) = v;
    }
}

// ---------------------------------------------------------------------------
// addred: o = a + b elementwise (float4), for split-K partials.
// ---------------------------------------------------------------------------
__global__ __launch_bounds__(256) void addred(const float4* __restrict__ a,
                                              const float4* __restrict__ bsrc,
                                              float4* __restrict__ o, int n4)
{
    int i = blockIdx.x * 256 + threadIdx.x;
    int st = gridDim.x * 256;
    for (; i < n4; i += st){
        float4 x = a[i], y = bsrc[i];
        o[i] = make_float4(x.x + y.x, x.y + y.y, x.z + y.z, x.w + y.w);
    }
}

// ---------------------------------------------------------------------------
// wc_mm: Wc = eWp @ vWp  (128x128x128 fp32)
// ---------------------------------------------------------------------------
__global__ __launch_bounds__(256) void wc_mm(const float* __restrict__ eWp,
                                             const float* __restrict__ vWp,
                                             float* __restrict__ Wc)
{
    int i = blockIdx.x * 2 + (threadIdx.x >> 7);
    int j = threadIdx.x & 127;
    float acc = 0.f;
    for (int k = 0; k < 128; k++)
        acc += eWp[i * 128 + k] * vWp[k * 128 + j];
    Wc[i * 128 + j] = acc;
}

// ---------------------------------------------------------------------------
// rowmm: C[n,:] = A[n,:] @ W^T, fp32. In-place safe (A rows fully staged
// into LDS before any C store; blocks own disjoint rows).
// ---------------------------------------------------------------------------
__global__ __launch_bounds__(256) void rowmm(const float* A,
                                             const float* __restrict__ W,
                                             float* C)
{
    __shared__ alignas(16) float lA[32][132];
    __shared__ alignas(16) float lW[64][140];
    const int t = threadIdx.x;
    const int row0 = blockIdx.x * 32;
    const float4* A4 = (const float4*)A;
    const float4* W4 = (const float4*)W;

    #pragma unroll
    for (int i = 0; i < 4; i++){
        int idx = t + 256 * i;
        int r = idx >> 5, k4 = idx & 31;
        *(float4*)&lA[r][k4 * 4] = A4[(size_t)(row0 + r) * 32 + k4];
    }
    const int qq = t >> 5;
    const int cc = t & 31;

    #pragma unroll
    for (int ph = 0; ph < 2; ph++){
        __syncthreads();
        #pragma unroll
        for (int i = 0; i < 8; i++){
            int idx = t + 256 * i;
            int c = idx >> 5, k4 = idx & 31;
            *(float4*)&lW[c][k4 * 4] = W4[(size_t)(ph * 64 + c) * 32 + k4];
        }
        __syncthreads();
        float s[4][2] = {};
        for (int k4 = 0; k4 < 32; k4++){
            float4 w0 = *(const float4*)&lW[cc][k4 * 4];
            float4 w1 = *(const float4*)&lW[cc + 32][k4 * 4];
            #pragma unroll
            for (int j = 0; j < 4; j++){
                float4 a = *(const float4*)&lA[qq + 8 * j][k4 * 4];
                s[j][0] += a.x * w0.x + a.y * w0.y + a.z * w0.z + a.w * w0.w;
                s[j][1] += a.x * w1.x + a.y * w1.y + a.z * w1.z + a.w * w1.w;
            }
        }
        #pragma unroll
        for (int j = 0; j < 4; j++){
            size_t ro = (size_t)(row0 + qq + 8 * j) * DD + ph * 64;
            C[ro + cc]      = s[j][0];
            C[ro + cc + 32] = s[j][1];
        }
    }
}

// ---------------------------------------------------------------------------
// Online softmax over e (two passes, coalesced).
// ---------------------------------------------------------------------------
__global__ __launch_bounds__(256) void sm_part(const float* __restrict__ eatt,
                                               float* __restrict__ part)
{
    const int b = blockIdx.x, slab = blockIdx.y;
    const int t = threadIdx.x;
    const int dl = t & 127, eh = t >> 7;
    const size_t base = (size_t)b * EE * DD + dl;
    const int e0 = slab * 256;
    float m = -1e30f;
    for (int s = 0; s < 128; s++)
        m = fmaxf(m, eatt[base + (size_t)(e0 + eh + 2 * s) * DD]);
    float l = 0.f;
    for (int s = 0; s < 128; s++)
        l += __expf(eatt[base + (size_t)(e0 + eh + 2 * s) * DD] - m);
    __shared__ float red[2][128][2];
    red[eh][dl][0] = m; red[eh][dl][1] = l;
    __syncthreads();
    if (t < 128){
        float m0 = red[0][t][0], l0 = red[0][t][1];
        float m1 = red[1][t][0], l1 = red[1][t][1];
        float M = fmaxf(m0, m1);
        float L = l0 * __expf(m0 - M) + l1 * __expf(m1 - M);
        float* p = part + ((size_t)(b * 8 + slab) * DD + t) * 2;
        p[0] = M; p[1] = L;
    }
}

__global__ __launch_bounds__(256) void sm_apply(float* __restrict__ eatt,
                                                const float* __restrict__ agg,
                                                const float* __restrict__ part)
{
    const int b = blockIdx.x, sl = blockIdx.y;
    const int t = threadIdx.x;
    __shared__ float mv[128], iv[128];
    if (t < 128){
        float mbuf[8], lbuf[8];
        float M = -1e30f;
        #pragma unroll
        for (int s = 0; s < 8; s++){
            const float* p = part + ((size_t)(b * 8 + s) * DD + t) * 2;
            mbuf[s] = p[0]; lbuf[s] = p[1];
            M = fmaxf(M, mbuf[s]);
        }
        float L = 0.f;
        #pragma unroll
        for (int s = 0; s < 8; s++) L += lbuf[s] * __expf(mbuf[s] - M);
        mv[t] = M; iv[t] = 1.f / L;
    }
    __syncthreads();
    const int dl = t & 127, eh = t >> 7;
    const size_t base = (size_t)b * EE * DD + dl;
    const int e0 = sl * 128;
    for (int s = 0; s < 64; s++){
        size_t ix = base + (size_t)(e0 + eh + 2 * s) * DD;
        eatt[ix] = agg[ix] * __expf(eatt[ix] - mv[dl]) * iv[dl];
    }
}

// ---------------------------------------------------------------------------
// Pipeline (layer recursion = fixed point; ec_Wa dead; associativity:
//   eatt = agg@vWa^T,  node = (inc@P) @ (eWp@vWp)^T):
//  1. bits = pack(inc); bitsT = bitT(bits)
//  2. featT = T(feat) f16
//  3. big1 (bitsT x featT) x2 K-slices -> p0,p1 ; agg = p0+p1
//  4. eatt = agg@vWa^T ; softmax -> P (in-place)
//  5. edge = P@vWp^T (OUT2) ; PT = T(P) f16 ; Wc = eWp@vWp
//  6. Q = bits x PT ; node = Q@Wc^T in-place (OUT1)
// Memory: ws[0,8M)=bits; ws[8,16M)=bitsT then PT; ws[12M)=Wc.
// d_out: node[0,8M)=featT->agg; node[8,16M)=p0->eatt/P; edge=p1->part->edge.
// ---------------------------------------------------------------------------
extern "C" void kernel_launch(void* const* d_in, const int* in_sizes, int n_in,
                              void* d_out, int out_size, void* d_ws, size_t ws_size,
                              hipStream_t stream)
{
    const float* feat = (const float*)d_in[0];
    const float* inc  = (const float*)d_in[1];
    const float* vWa  = (const float*)d_in[2];
    const float* vWp  = (const float*)d_in[3];
    const float* eWp  = (const float*)d_in[6];

    float* node_out = (float*)d_out;
    float* edge_out = node_out + (size_t)BB * MM * DD;      // +4194304

    float* p0    = node_out + 2097152;                      // node[8,16M)
    // p1 = p0 + 2097152 == edge region (contiguous with p0)
    _Float16* featT = (_Float16*)node_out;                  // node[0,8M)
    float* agg   = node_out;                                // over featT (after big1)
    float* eattP = node_out + 2097152;                      // over p0 (after addred)
    float* part  = edge_out;                                // over p1 (after addred)

    char* w = (char*)d_ws;
    unsigned long long* bits  = (unsigned long long*)w;               // [0,8M)
    unsigned long long* bitsT = (unsigned long long*)(w + ((size_t)8 << 20)); // [8,16M)
    _Float16* PT = (_Float16*)(w + ((size_t)8 << 20));                // over bitsT
    float* Wc = (float*)(w + ((size_t)12 << 20));                     // 64 KB

    dim3 blk(256);

    // 1. bit layouts
    bitpack<<<dim3(2048), blk, 0, stream>>>(inc, bits);
    bit_transpose<<<dim3(EE / 64, MM / 256, BB), blk, 0, stream>>>(bits, bitsT);
    // 2. featT = f16(feat^T)
    transpose_to16<<<dim3((MM / 64) * (DD / 64), BB), blk, 0, stream>>>(feat, featT, MM, DD);
    // 3. agg = inc^T @ feat  (split-K x2, then add)
    bitgemm<<<dim3(EE / 128, BB, 2), blk, 0, stream>>>(
        (const uint4*)bitsT, featT, p0, EE, MM, 2048, 2097152u);
    addred<<<dim3(1024), blk, 0, stream>>>(
        (const float4*)p0, (const float4*)(p0 + 2097152), (float4*)agg, 524288);
    // 4. eatt = agg @ vWa^T ; P = agg * softmax_e(eatt)
    rowmm<<<dim3(BB * EE / 32), blk, 0, stream>>>(agg, vWa, eattP);
    sm_part <<<dim3(BB, 8),  blk, 0, stream>>>(eattP, part);
    sm_apply<<<dim3(BB, 16), blk, 0, stream>>>(eattP, agg, part);
    // 5. edge = P @ vWp^T (OUT2); PT = f16(P^T); Wc = eWp @ vWp
    rowmm<<<dim3(BB * EE / 32), blk, 0, stream>>>(eattP, vWp, edge_out);
    transpose_to16<<<dim3((EE / 64) * (DD / 64), BB), blk, 0, stream>>>(eattP, PT, EE, DD);
    wc_mm<<<dim3(64), blk, 0, stream>>>(eWp, vWp, Wc);
    // 6. Q = inc @ P -> node ; node = Q @ Wc^T (in-place, OUT1)
    bitgemm<<<dim3(MM / 128, BB, 1), blk, 0, stream>>>(
        (const uint4*)bits, PT, node_out, MM, EE, 2048, 0u);
    rowmm<<<dim3(BB * MM / 32), blk, 0, stream>>>(node_out, Wc, node_out);
}